// Round 3
// baseline (222.039 us; speedup 1.0000x reference)
//
#include <hip/hip_runtime.h>
#include <math.h>

#define S_LEN 512
#define D_DIM 256
#define SLICE (S_LEN * D_DIM)   // 131072

typedef _Float16 half8  __attribute__((ext_vector_type(8)));
typedef _Float16 half4v __attribute__((ext_vector_type(4)));
typedef float   floatx4 __attribute__((ext_vector_type(4)));

// ---------------------------------------------------------------------------
// WlhT[d][e] = fp16(Wl[e][d] + (e==d))     (raw + raw@Wl == raw@(I+Wl))
// ---------------------------------------------------------------------------
__global__ __launch_bounds__(256) void prep_wl(const float* __restrict__ Wl,
                                               _Float16* __restrict__ WlhT)
{
    const int d = blockIdx.x, e = threadIdx.x;
    float v = Wl[e * D_DIM + d] + (e == d ? 1.0f : 0.0f);
    WlhT[d * D_DIM + e] = (_Float16)v;
}

// ---------------------------------------------------------------------------
// y = x + x@W + b  for [512,256]@[256,256]; 4 rows/block (baseline shape).
// k,q cast to fp16 at the store (identical rounding to fp32-store + cvt).
// ---------------------------------------------------------------------------
__global__ __launch_bounds__(256) void linres3(
    const float* __restrict__ xk, const float* __restrict__ Wk,
    const float* __restrict__ bk, _Float16* __restrict__ yk16,
    const float* __restrict__ xq, const float* __restrict__ Wq,
    const float* __restrict__ bq, _Float16* __restrict__ yq16,
    const float* __restrict__ xv, const float* __restrict__ Wv,
    const float* __restrict__ bv, float* __restrict__ yv)
{
    __shared__ float xs[4][D_DIM];
    const int r0 = blockIdx.x * 4;
    const int sel = blockIdx.y;
    const float* x = sel == 0 ? xk : (sel == 1 ? xq : xv);
    const float* W = sel == 0 ? Wk : (sel == 1 ? Wq : Wv);
    const float* b = sel == 0 ? bk : (sel == 1 ? bq : bv);

    const int tid = threadIdx.x;
    #pragma unroll
    for (int t = 0; t < 4; ++t) xs[t][tid] = x[(r0 + t) * D_DIM + tid];
    __syncthreads();
    const float bv_ = b[tid];
    float acc[4];
    #pragma unroll
    for (int i = 0; i < 4; ++i) acc[i] = xs[i][tid] + bv_;
    #pragma unroll 4
    for (int e = 0; e < D_DIM; ++e) {
        const float w = W[e * D_DIM + tid];
        #pragma unroll
        for (int i = 0; i < 4; ++i) acc[i] += xs[i][e] * w;
    }
    if (sel == 2) {
        #pragma unroll
        for (int i = 0; i < 4; ++i) yv[(r0 + i) * D_DIM + tid] = acc[i];
    } else {
        _Float16* y16 = sel == 0 ? yk16 : yq16;
        #pragma unroll
        for (int i = 0; i < 4; ++i) y16[(r0 + i) * D_DIM + tid] = (_Float16)acc[i];
    }
}

// ---------------------------------------------------------------------------
// Final linear with partial-sum fusion: x = sum_c po[c]; out = x + x@W + b
// ---------------------------------------------------------------------------
__global__ __launch_bounds__(256) void linres_sum(
    const float* __restrict__ po, const float* __restrict__ W,
    const float* __restrict__ b, float* __restrict__ y)
{
    __shared__ float xs[4][D_DIM];
    const int tid = threadIdx.x;
    const int r0  = blockIdx.x * 4;
    #pragma unroll
    for (int t = 0; t < 4; ++t) {
        float s = 0.f;
        #pragma unroll
        for (int c = 0; c < 16; ++c)
            s += po[(size_t)c * SLICE + (r0 + t) * D_DIM + tid];
        xs[t][tid] = s;
    }
    __syncthreads();
    const float bv_ = b[tid];
    float acc[4];
    #pragma unroll
    for (int i = 0; i < 4; ++i) acc[i] = xs[i][tid] + bv_;
    #pragma unroll 4
    for (int e = 0; e < D_DIM; ++e) {
        const float w = W[e * D_DIM + tid];
        #pragma unroll
        for (int i = 0; i < 4; ++i) acc[i] += xs[i][e] * w;
    }
    #pragma unroll
    for (int i = 0; i < 4; ++i) y[(r0 + i) * D_DIM + tid] = acc[i];
}

// ---------------------------------------------------------------------------
// Stage 64x256 fp16 q tile into fragment-major LDS (R3/R7/R11-proven):
// fb = mt*8+kk; slot = quad*16+l16; addr16 = fb*64 + slot. Conflict-free.
// LDS is now used ONCE (staging + reg-fill), not re-read per s-iteration.
// ---------------------------------------------------------------------------
__device__ __forceinline__ void stage_q(const _Float16* __restrict__ qh,
                                        _Float16* __restrict__ Afrag,
                                        int sq0, int tid)
{
    const int i   = tid & 63;   // row within tile
    const int qtr = tid >> 6;   // e-quarter (64 elems)
    const int mt = i >> 4, l16 = i & 15;
    const half8* src = (const half8*)(qh + (size_t)(sq0 + i) * D_DIM + qtr * 64);
    #pragma unroll
    for (int u = 0; u < 8; ++u) {
        const int eb   = qtr * 8 + u;           // e-block (8 halfs) 0..31
        const int kk   = eb >> 2, quad = eb & 3;
        const int addr16 = (mt * 8 + kk) * 64 + quad * 16 + l16;
        *(half8*)(Afrag + addr16 * 8) = src[u];
    }
}

// Same layout for a 32-row tile (mt in {0,1}), 4 half8 per thread (R8-proven).
__device__ __forceinline__ void stage_q32(const _Float16* __restrict__ qh,
                                          _Float16* __restrict__ Afrag,
                                          int sq0, int tid)
{
    const int i   = tid & 31;   // row within tile
    const int oct = tid >> 5;   // e-eighth (32 halfs)
    const int mt = i >> 4, l16 = i & 15;
    const half8* src = (const half8*)(qh + (size_t)(sq0 + i) * D_DIM);
    #pragma unroll
    for (int u = 0; u < 4; ++u) {
        const int eb   = oct * 4 + u;           // e-block (8 halfs) 0..31
        const int kk   = eb >> 2, quad = eb & 3;
        const int addr16 = (mt * 8 + kk) * 64 + quad * 16 + l16;
        *(half8*)(Afrag + addr16 * 8) = src[eb];
    }
}

// ---------------------------------------------------------------------------
// Stats: per-(sk,d) tile-partial (max, sum |L| e^(L-max)) over 64 sq rows.
// R3 restructure: the inner loop previously re-read the SAME 32 KB of A
// fragments from LDS every s-iteration (16x redundant; ~70% LDS-pipe busy
// per-CU was the hidden bound — MfmaUtil 22 + VALUBusy 34 left 44% idle,
// bank conflicts 0). Now: y-split 2->4 so each wave owns 64sq x 16d ->
// A fragments fit in registers (afr[4][8] = 128 VGPR, wl[8] = 32,
// k8a[8] = 32, acc 16; ~225 total). LDS read ONCE at startup, ZERO LDS in
// the s-loop. Total MFMA/VALU work across grid unchanged (half per wave,
// twice the waves). Grid (8,4,32) = 1024 blocks.
// kk loop FULLY unrolled (regs must stay static-indexed — the R7-R9 bug).
// ---------------------------------------------------------------------------
__global__ __launch_bounds__(256, 2) void stats_mfma(
    const _Float16* __restrict__ qh, const _Float16* __restrict__ kh,
    const _Float16* __restrict__ WlhT, const float* __restrict__ bl,
    float* __restrict__ pm, float* __restrict__ ps)
{
    __shared__ _Float16 Afrag[32 * 64 * 8];   // 32 KB

    const int tid  = threadIdx.x;
    const int lane = tid & 63, wave = tid >> 6;
    const int quad = lane >> 4, l16 = lane & 15;
    const int sqt  = blockIdx.x, sq0 = sqt * 64;
    const int dw   = blockIdx.y * 64 + wave * 16;   // 16 d per wave
    const int sk0  = blockIdx.z * 16;

    stage_q(qh, Afrag, sq0, tid);

    // wl for this wave's 16 d columns (one nt)
    half8 wl[8];
    const int d = dw + l16;
    #pragma unroll
    for (int kk = 0; kk < 8; ++kk)
        wl[kk] = *(const half8*)(WlhT + (size_t)d * D_DIM + kk * 32 + quad * 8);
    const float bl_r = bl[d];

    __syncthreads();

    // One-time reg-fill of all A fragments; LDS dead afterwards.
    half8 afr[4][8];
    #pragma unroll
    for (int mt = 0; mt < 4; ++mt)
        #pragma unroll
        for (int kk = 0; kk < 8; ++kk)
            afr[mt][kk] = *(const half8*)(Afrag + ((mt * 8 + kk) * 64 + lane) * 8);

    #pragma unroll 1
    for (int s = 0; s < 16; ++s) {
        const int sk = sk0 + s;

        // issue all 8 k-row loads up-front (independent, L2-broadcast)
        half8 k8a[8];
        #pragma unroll
        for (int kk = 0; kk < 8; ++kk)
            k8a[kk] = *(const half8*)(kh + (size_t)sk * D_DIM + kk * 32 + quad * 8);

        floatx4 acc[4];
        #pragma unroll
        for (int mt = 0; mt < 4; ++mt)
            acc[mt] = (floatx4){0.f, 0.f, 0.f, 0.f};

        #pragma unroll
        for (int kk = 0; kk < 8; ++kk) {
            const half8 bf = wl[kk] * k8a[kk];
            #pragma unroll
            for (int mt = 0; mt < 4; ++mt)
                acc[mt] = __builtin_amdgcn_mfma_f32_16x16x32_f16(
                    afr[mt][kk], bf, acc[mt], 0, 0, 0);
        }

        // epilogue: L in-place into acc (saves 16 regs vs separate Lv)
        float tmax = -1e30f;
        #pragma unroll
        for (int mt = 0; mt < 4; ++mt)
            #pragma unroll
            for (int r = 0; r < 4; ++r) {
                const float L = acc[mt][r] + bl_r;
                acc[mt][r] = L;
                tmax = fmaxf(tmax, L);
            }
        float tsum = 0.f;
        #pragma unroll
        for (int mt = 0; mt < 4; ++mt)
            #pragma unroll
            for (int r = 0; r < 4; ++r)
                tsum += fabsf(acc[mt][r]) * __expf(acc[mt][r] - tmax);

        float m = tmax, ss = tsum;
        #pragma unroll
        for (int mask = 16; mask <= 32; mask <<= 1) {
            float m2 = __shfl_xor(m, mask, 64);
            float s2 = __shfl_xor(ss, mask, 64);
            float M  = fmaxf(m, m2);
            ss = ss * __expf(m - M) + s2 * __expf(m2 - M);
            m = M;
        }
        if (quad == 0) {
            pm[((size_t)sqt * S_LEN + sk) * D_DIM + d] = m;
            ps[((size_t)sqt * S_LEN + sk) * D_DIM + d] = ss;
        }
    }
}

// ---------------------------------------------------------------------------
// Merge the 8 sq-tile partials -> mbuf, sbuf.
// ---------------------------------------------------------------------------
__global__ __launch_bounds__(256) void reduce_ms(
    const float* __restrict__ pm, const float* __restrict__ ps,
    float* __restrict__ mbuf, float* __restrict__ sbuf)
{
    const int idx = blockIdx.x * 256 + threadIdx.x;   // (sk,d), 131072 total
    float mv[8], sv[8];
    #pragma unroll
    for (int t = 0; t < 8; ++t) {
        mv[t] = pm[(size_t)t * SLICE + idx];
        sv[t] = ps[(size_t)t * SLICE + idx];
    }
    float M = mv[0];
    #pragma unroll
    for (int t = 1; t < 8; ++t) M = fmaxf(M, mv[t]);
    float ss = 0.f;
    #pragma unroll
    for (int t = 0; t < 8; ++t) ss += sv[t] * __expf(mv[t] - M);
    mbuf[idx] = M;
    sbuf[idx] = ss;
}

// ---------------------------------------------------------------------------
// Accum: recompute L, p = L e^(L-m)/(S+1); o += v[sk,d]*p over 32 sk.
// Grid (16,2,16) = 512 blocks — baseline shape (proven).
// R3: A fragments hoisted to registers once (afr[2][8] = 64 VGPR; with
// wl 64 + o 32 + acc 32 + temps ~= 218 total) -> ZERO LDS reads in the
// 32-iteration s-loop (was 16 ds_read_b128 per s). Epilogue scalars
// stay hoisted above the MFMA burst (R2, kept).
// ---------------------------------------------------------------------------
__global__ __launch_bounds__(256, 2) void accum_mfma(
    const _Float16* __restrict__ qh, const _Float16* __restrict__ kh,
    const _Float16* __restrict__ WlhT, const float* __restrict__ bl,
    const float* __restrict__ mbuf, const float* __restrict__ sbuf,
    const float* __restrict__ vbuf, float* __restrict__ po)
{
    __shared__ _Float16 Afrag[16 * 64 * 8];   // 16 KB

    const int tid  = threadIdx.x;
    const int lane = tid & 63, wave = tid >> 6;
    const int quad = lane >> 4, l16 = lane & 15;
    const int sq0  = blockIdx.x * 32;
    const int dw   = blockIdx.y * 128 + wave * 32;
    const int chunk = blockIdx.z;
    const int sk0  = chunk * 32;

    stage_q32(qh, Afrag, sq0, tid);

    half8 wl[2][8];
    #pragma unroll
    for (int nt = 0; nt < 2; ++nt) {
        const int d = dw + nt * 16 + l16;
        #pragma unroll
        for (int kk = 0; kk < 8; ++kk)
            wl[nt][kk] = *(const half8*)(WlhT + (size_t)d * D_DIM + kk * 32 + quad * 8);
    }
    float bl_r[2];
    #pragma unroll
    for (int nt = 0; nt < 2; ++nt)
        bl_r[nt] = bl[dw + nt * 16 + l16];

    __syncthreads();

    // One-time reg-fill of A fragments; LDS dead afterwards.
    half8 afr[2][8];
    #pragma unroll
    for (int mt = 0; mt < 2; ++mt)
        #pragma unroll
        for (int kk = 0; kk < 8; ++kk)
            afr[mt][kk] = *(const half8*)(Afrag + ((mt * 8 + kk) * 64 + lane) * 8);

    floatx4 o[2][2];
    #pragma unroll
    for (int mt = 0; mt < 2; ++mt)
        #pragma unroll
        for (int nt = 0; nt < 2; ++nt)
            o[mt][nt] = (floatx4){0.f, 0.f, 0.f, 0.f};

    #pragma unroll 1
    for (int s = 0; s < 32; ++s) {
        const int sk = sk0 + s;

        // hoisted epilogue scalars: issue loads before the MFMA burst
        float m_r2[2], w_r2[2];
        #pragma unroll
        for (int nt = 0; nt < 2; ++nt) {
            const int d = dw + nt * 16 + l16;
            m_r2[nt] = mbuf[(size_t)sk * D_DIM + d];
            const float sden = sbuf[(size_t)sk * D_DIM + d];
            const float vv   = vbuf[(size_t)sk * D_DIM + d];
            w_r2[nt] = vv / (sden + 1.0f);
        }

        floatx4 acc[2][2];
        #pragma unroll
        for (int mt = 0; mt < 2; ++mt)
            #pragma unroll
            for (int nt = 0; nt < 2; ++nt)
                acc[mt][nt] = (floatx4){0.f, 0.f, 0.f, 0.f};

        #pragma unroll
        for (int kk = 0; kk < 8; ++kk) {
            const half8 k8 = *(const half8*)(kh + (size_t)sk * D_DIM + kk * 32 + quad * 8);
            half8 bf[2];
            #pragma unroll
            for (int nt = 0; nt < 2; ++nt)
                bf[nt] = wl[nt][kk] * k8;
            #pragma unroll
            for (int mt = 0; mt < 2; ++mt)
                #pragma unroll
                for (int nt = 0; nt < 2; ++nt)
                    acc[mt][nt] = __builtin_amdgcn_mfma_f32_16x16x32_f16(
                        afr[mt][kk], bf[nt], acc[mt][nt], 0, 0, 0);
        }

        #pragma unroll
        for (int nt = 0; nt < 2; ++nt) {
            const float m_r = m_r2[nt];
            const float w_r = w_r2[nt];
            #pragma unroll
            for (int mt = 0; mt < 2; ++mt)
                #pragma unroll
                for (int r = 0; r < 4; ++r) {
                    const float L = acc[mt][nt][r] + bl_r[nt];
                    const float t = __expf(L - m_r);
                    o[mt][nt][r] += w_r * (L * t);
                }
        }
    }

    float* dst = po + (size_t)chunk * SLICE;
    #pragma unroll
    for (int mt = 0; mt < 2; ++mt)
        #pragma unroll
        for (int nt = 0; nt < 2; ++nt)
            #pragma unroll
            for (int r = 0; r < 4; ++r) {
                const int row = sq0 + mt * 16 + quad * 4 + r;
                const int col = dw + nt * 16 + l16;
                dst[(size_t)row * D_DIM + col] = o[mt][nt][r];
            }
}

// ---------------------------------------------------------------------------
extern "C" void kernel_launch(void* const* d_in, const int* in_sizes, int n_in,
                              void* d_out, int out_size, void* d_ws, size_t ws_size,
                              hipStream_t stream)
{
    const float* query = (const float*)d_in[0];
    const float* key   = (const float*)d_in[1];
    const float* value = (const float*)d_in[2];
    const float* Wk  = (const float*)d_in[3];
    const float* bk  = (const float*)d_in[4];
    const float* Wq  = (const float*)d_in[5];
    const float* bq  = (const float*)d_in[6];
    const float* Wva = (const float*)d_in[7];
    const float* bva = (const float*)d_in[8];
    const float* Wl  = (const float*)d_in[9];
    const float* bl  = (const float*)d_in[10];
    const float* Wvo = (const float*)d_in[11];
    const float* bvo = (const float*)d_in[12];

    const int MAT = SLICE;                    // 131072
    float* ws   = (float*)d_ws;
    // R11-proven footprint (kbuf/qbuf fp32 slots unused — linres3 writes
    // kh/qh fp16 directly).
    float* vbuf = ws + 2 * MAT;
    float* mbuf = ws + 3 * MAT;
    float* sbuf = ws + 4 * MAT;
    _Float16* WlhT = (_Float16*)(ws + 6 * MAT);            // 128 KB
    _Float16* kh   = (_Float16*)(ws + 6 * MAT + 32768);    // 256 KB
    _Float16* qh   = kh + MAT;                             // 256 KB
    float* pm  = ws + 6 * MAT + 32768 + 2 * 65536;         // 4 MB
    float* ps  = pm + 8 * MAT;                             // 4 MB
    float* po  = pm;   // 16*MAT floats (8 MB), pm/ps dead after reduce_ms
    float* out = (float*)d_out;

    prep_wl<<<256, 256, 0, stream>>>(Wl, WlhT);
    linres3<<<dim3(128, 3), 256, 0, stream>>>(key, Wk, bk, kh,
                                              query, Wq, bq, qh,
                                              value, Wva, bva, vbuf);

    stats_mfma<<<dim3(8, 4, 32), 256, 0, stream>>>(qh, kh, WlhT, bl, pm, ps);
    reduce_ms<<<512, 256, 0, stream>>>(pm, ps, mbuf, sbuf);
    accum_mfma<<<dim3(16, 2, 16), 256, 0, stream>>>(qh, kh, WlhT, bl,
                                                    mbuf, sbuf, vbuf, po);

    linres_sum<<<128, 256, 0, stream>>>(po, Wvo, bvo, out);
}